// Round 1
// 3922.079 us; speedup vs baseline: 1.1431x; 1.1431x over previous
//
#include <hip/hip_runtime.h>
#include <cmath>

#define DEV_INLINE __device__ __forceinline__

constexpr int B_ = 8, T_ = 16, INPUT_ = 64, OUTPUT_ = 128;
constexpr int N_ = 256, H_ = 256, KQ_ = 256, S_ = 256, G_ = 1024; // G_ = 4*H
constexpr int NIN_ = 32;
constexpr float SCALE_ = 0.0625f; // 1/sqrt(256)

DEV_INLINE float sigmoid_(float x) { return 1.0f / (1.0f + expf(-x)); }
DEV_INLINE void fma4(float4& a, const float4& w, float s) {
    a.x += w.x * s; a.y += w.y * s; a.z += w.z * s; a.w += w.w * s;
}

// ---------------------------------------------------------------------------
// pnmm256: out[b][n][c] = sum_h in[b][n][h] * W[n-nW0][h][c] + bias[n-nW0][c]
// One 256-thread block per (n, stream). 4 waves split the K dim (64 rows
// each), partials reduced through LDS, bias (+optional relu) fused.
// grid = (nCount, nz); blockIdx.y selects (W,bias,out) triplet for fusion of
// sender / query / key (z=3) or query / key init (z=2).
// ---------------------------------------------------------------------------
__global__ __launch_bounds__(256)
void pnmm256_kernel(const float* __restrict__ in,
                    const float* __restrict__ W0, const float* __restrict__ bias0, float* __restrict__ O0,
                    const float* __restrict__ W1, const float* __restrict__ bias1, float* __restrict__ O1,
                    const float* __restrict__ W2, const float* __restrict__ bias2, float* __restrict__ O2,
                    int n0, int nW0, int relu)
{
    const int ny = blockIdx.x;
    const int n = n0 + ny;
    const int nw = n - nW0;
    const float* W; const float* bias; float* O;
    if (blockIdx.y == 0)      { W = W0; bias = bias0; O = O0; }
    else if (blockIdx.y == 1) { W = W1; bias = bias1; O = O1; }
    else                      { W = W2; bias = bias2; O = O2; }

    const int tid = threadIdx.x;
    const int wv = tid >> 6;          // wave id 0..3 -> K split
    const int lane = tid & 63;
    const int c0 = lane * 4;
    const int h0 = wv * 64;

    __shared__ float sh[256 * 8];     // staging [hh][b]   (8 KB)
    __shared__ float psum[4][2048];   // per-wave partials (32 KB)

    for (int i = tid; i < 2048; i += 256) {
        int hh = i & 255, b = i >> 8;
        sh[hh * 8 + b] = in[(size_t)(b * N_ + n) * H_ + hh];
    }
    __syncthreads();

    const float* wp = W + ((size_t)nw * H_ + h0) * 256 + c0;
    float4 acc[8] = {};
    float4 bufA[8], bufB[8];
#pragma unroll
    for (int u = 0; u < 8; ++u) bufA[u] = *(const float4*)(wp + (size_t)u * 256);
#pragma unroll 1
    for (int hb = 0; hb < 64; hb += 8) {
        if (hb + 8 < 64) {
#pragma unroll
            for (int u = 0; u < 8; ++u)
                bufB[u] = *(const float4*)(wp + (size_t)(hb + 8 + u) * 256);
        }
#pragma unroll
        for (int u = 0; u < 8; ++u) {
            float4 w = bufA[u];
            const float* ip = &sh[(h0 + hb + u) * 8];
            float4 i0 = *(const float4*)ip;
            float4 i1 = *(const float4*)(ip + 4);
            fma4(acc[0], w, i0.x); fma4(acc[1], w, i0.y);
            fma4(acc[2], w, i0.z); fma4(acc[3], w, i0.w);
            fma4(acc[4], w, i1.x); fma4(acc[5], w, i1.y);
            fma4(acc[6], w, i1.z); fma4(acc[7], w, i1.w);
        }
#pragma unroll
        for (int u = 0; u < 8; ++u) bufA[u] = bufB[u];
    }
#pragma unroll
    for (int b = 0; b < 8; ++b)
        *(float4*)&psum[wv][b * 256 + c0] = acc[b];
    __syncthreads();

    for (int i = tid; i < 2048; i += 256) {
        int b = i >> 8, cc = i & 255;
        float s = psum[0][i] + psum[1][i] + psum[2][i] + psum[3][i]
                + bias[(size_t)nw * 256 + cc];
        if (relu) s = fmaxf(s, 0.f);
        O[(size_t)(b * N_ + n) * H_ + cc] = s;
    }
}

// ---------------------------------------------------------------------------
// gatescell: gates = lin @ w_ih + h @ w_hh + biases, then LSTM cell fused.
// One 512-thread block per neuron n: 2 K-splits of 128 rows (tid>>8), each
// thread owns 4 of the 1024 gate cols; partial reduce + cell via LDS.
// h/c rows for neuron n are block-private -> safe to read-modify-write.
// ---------------------------------------------------------------------------
__global__ __launch_bounds__(512)
void gatescell_kernel(const float* __restrict__ lin,      // [b][n][h], n>=32 valid
                      const float* __restrict__ rec_all,  // [t][b][32][h] (relu'd)
                      int t,
                      const float* __restrict__ wih, const float* __restrict__ whh,
                      const float* __restrict__ bih, const float* __restrict__ bhh,
                      float* __restrict__ c, float* __restrict__ h)
{
    const int n = blockIdx.x;
    const int tid = threadIdx.x;      // 0..511
    const int sp = tid >> 8;          // K split 0/1
    const int c0 = (tid & 255) * 4;   // gate col
    const int h0 = sp * 128;

    __shared__ float smem[8192];      // 32 KB, aliased
    float* shi = smem;                // [256][8] lstm_in
    float* shh = smem + 2048;         // [256][8] h
    float* glds = smem;               // [8][1024] gates (epilogue)

    for (int i = tid; i < 2048; i += 512) {
        int hh = i & 255, b = i >> 8;
        shh[hh * 8 + b] = h[(size_t)(b * N_ + n) * H_ + hh];
        shi[hh * 8 + b] = (n < NIN_)
            ? rec_all[(((size_t)t * 8 + b) * NIN_ + n) * H_ + hh]
            : lin[(size_t)(b * N_ + n) * H_ + hh];
    }
    __syncthreads();

    const float* wi = wih + ((size_t)n * H_ + h0) * G_ + c0;
    const float* wh = whh + ((size_t)n * H_ + h0) * G_ + c0;
    float4 acc[8] = {};
    float4 biA[4], bhA[4], biB[4], bhB[4];
#pragma unroll
    for (int u = 0; u < 4; ++u) {
        biA[u] = *(const float4*)(wi + (size_t)u * G_);
        bhA[u] = *(const float4*)(wh + (size_t)u * G_);
    }
#pragma unroll 1
    for (int hb = 0; hb < 128; hb += 4) {
        if (hb + 4 < 128) {
#pragma unroll
            for (int u = 0; u < 4; ++u) {
                biB[u] = *(const float4*)(wi + (size_t)(hb + 4 + u) * G_);
                bhB[u] = *(const float4*)(wh + (size_t)(hb + 4 + u) * G_);
            }
        }
#pragma unroll
        for (int u = 0; u < 4; ++u) {
            float4 a = biA[u];
            float4 hv = bhA[u];
            const float* ip = &shi[(h0 + hb + u) * 8];
            const float* hp = &shh[(h0 + hb + u) * 8];
            float4 i0 = *(const float4*)ip;
            float4 i1 = *(const float4*)(ip + 4);
            float4 h0v = *(const float4*)hp;
            float4 h1v = *(const float4*)(hp + 4);
            fma4(acc[0], a, i0.x); fma4(acc[0], hv, h0v.x);
            fma4(acc[1], a, i0.y); fma4(acc[1], hv, h0v.y);
            fma4(acc[2], a, i0.z); fma4(acc[2], hv, h0v.z);
            fma4(acc[3], a, i0.w); fma4(acc[3], hv, h0v.w);
            fma4(acc[4], a, i1.x); fma4(acc[4], hv, h1v.x);
            fma4(acc[5], a, i1.y); fma4(acc[5], hv, h1v.y);
            fma4(acc[6], a, i1.z); fma4(acc[6], hv, h1v.z);
            fma4(acc[7], a, i1.w); fma4(acc[7], hv, h1v.w);
        }
#pragma unroll
        for (int u = 0; u < 4; ++u) { biA[u] = biB[u]; bhA[u] = bhB[u]; }
    }
    __syncthreads();                  // staging dead; alias into glds
    if (sp == 1) {
#pragma unroll
        for (int b = 0; b < 8; ++b)
            *(float4*)&glds[b * 1024 + c0] = acc[b];
    }
    __syncthreads();
    if (sp == 0) {
        float4 bi = *(const float4*)&bih[(size_t)n * G_ + c0];
        float4 bh = *(const float4*)&bhh[(size_t)n * G_ + c0];
#pragma unroll
        for (int b = 0; b < 8; ++b) {
            float4 g = *(const float4*)&glds[b * 1024 + c0];
            g.x += acc[b].x + bi.x + bh.x;
            g.y += acc[b].y + bi.y + bh.y;
            g.z += acc[b].z + bi.z + bh.z;
            g.w += acc[b].w + bi.w + bh.w;
            *(float4*)&glds[b * 1024 + c0] = g;
        }
    }
    __syncthreads();
    // cell: gates layout [i(0:256) f(256:512) g(512:768) o(768:1024)]
#pragma unroll
    for (int e = 0; e < 4; ++e) {
        int idx = tid + 512 * e;      // 0..2047
        int b = idx >> 8, hx = idx & 255;
        float ig = glds[b * 1024 + 0   + hx];
        float fg = glds[b * 1024 + 256 + hx];
        float gg = glds[b * 1024 + 512 + hx];
        float og = glds[b * 1024 + 768 + hx];
        size_t off = (size_t)(b * N_ + n) * H_ + hx;
        float cv = c[off];
        float cn = sigmoid_(fg) * cv + sigmoid_(ig) * tanhf(gg);
        c[off] = cn;
        h[off] = sigmoid_(og) * tanhf(cn);
    }
}

// ---------------------------------------------------------------------------
// rec_in_all: lin_in[t][b][n][h] = relu(x_t @ w_rec_input + b), all T upfront
// (depends only on x). grid (32 n, 16 t).
// ---------------------------------------------------------------------------
__global__ __launch_bounds__(256)
void rec_in_all_kernel(const float* __restrict__ x,
                       const float* __restrict__ w_ri, const float* __restrict__ b_ri,
                       float* __restrict__ rec_all)
{
    __shared__ float sh[INPUT_ * 8];
    const int n = blockIdx.x;
    const int t = blockIdx.y;
    const int tid = threadIdx.x;
    for (int i = tid; i < INPUT_ * 8; i += 256) {
        int hh = i & 63, b = i >> 6;
        sh[hh * 8 + b] = x[((size_t)b * T_ + t) * INPUT_ + hh];
    }
    __syncthreads();
    const float* wp = w_ri + (size_t)n * INPUT_ * H_ + tid;
    float acc[8] = {};
#pragma unroll 8
    for (int hh = 0; hh < INPUT_; ++hh) {
        float w = wp[(size_t)hh * H_];
        float4 i0 = *(const float4*)&sh[hh * 8];
        float4 i1 = *(const float4*)&sh[hh * 8 + 4];
        acc[0] += w * i0.x; acc[1] += w * i0.y; acc[2] += w * i0.z; acc[3] += w * i0.w;
        acc[4] += w * i1.x; acc[5] += w * i1.y; acc[6] += w * i1.z; acc[7] += w * i1.w;
    }
    float bv = b_ri[n * H_ + tid];
#pragma unroll
    for (int b = 0; b < 8; ++b)
        rec_all[(((size_t)t * 8 + b) * NIN_ + n) * H_ + tid] = fmaxf(acc[b] + bv, 0.f);
}

// ---------------------------------------------------------------------------
// scores[b][n][m] = SCALE * sum_h Q[b][n][h] * K[b][m][h]   (A @ B^T, 64x64)
// ---------------------------------------------------------------------------
__global__ void scores_kernel(const float* __restrict__ Q, const float* __restrict__ Kb,
                              float* __restrict__ sc)
{
    __shared__ float As[16][64];
    __shared__ float Bs[16][64];
    const int b = blockIdx.y;
    const int tile = blockIdx.x;
    const int row0 = (tile >> 2) * 64;
    const int col0 = (tile & 3) * 64;
    const int tid = threadIdx.x;
    const int tx = tid & 15, ty = tid >> 4;
    const int lr = tid >> 2;
    const int kq = (tid & 3) * 4;
    const float* Qb = Q + (size_t)b * N_ * KQ_;
    const float* Kbb = Kb + (size_t)b * N_ * KQ_;
    float acc[4][4] = {};
    for (int kt = 0; kt < KQ_; kt += 16) {
        float4 av = *(const float4*)&Qb[(size_t)(row0 + lr) * KQ_ + kt + kq];
        float4 bv = *(const float4*)&Kbb[(size_t)(col0 + lr) * KQ_ + kt + kq];
        __syncthreads();
        As[kq + 0][lr] = av.x; As[kq + 1][lr] = av.y; As[kq + 2][lr] = av.z; As[kq + 3][lr] = av.w;
        Bs[kq + 0][lr] = bv.x; Bs[kq + 1][lr] = bv.y; Bs[kq + 2][lr] = bv.z; Bs[kq + 3][lr] = bv.w;
        __syncthreads();
#pragma unroll
        for (int k = 0; k < 16; ++k) {
            float4 a = *(const float4*)&As[k][ty * 4];
            float4 c = *(const float4*)&Bs[k][tx * 4];
            acc[0][0] += a.x * c.x; acc[0][1] += a.x * c.y; acc[0][2] += a.x * c.z; acc[0][3] += a.x * c.w;
            acc[1][0] += a.y * c.x; acc[1][1] += a.y * c.y; acc[1][2] += a.y * c.z; acc[1][3] += a.y * c.w;
            acc[2][0] += a.z * c.x; acc[2][1] += a.z * c.y; acc[2][2] += a.z * c.z; acc[2][3] += a.z * c.w;
            acc[3][0] += a.w * c.x; acc[3][1] += a.w * c.y; acc[3][2] += a.w * c.z; acc[3][3] += a.w * c.w;
        }
    }
#pragma unroll
    for (int i = 0; i < 4; ++i) {
        float4 r = make_float4(acc[i][0] * SCALE_, acc[i][1] * SCALE_,
                               acc[i][2] * SCALE_, acc[i][3] * SCALE_);
        *(float4*)&sc[((size_t)b * N_ + row0 + ty * 4 + i) * N_ + col0 + tx * 4] = r;
    }
}

// ---------------------------------------------------------------------------
// smctx: ctx = softmax(sc, axis=m) @ prev, fused. Block covers 64 rows x 64
// cols of ctx; loads its 64 FULL score rows transposed into LDS, does
// max/exp/sum in-block, defers the 1/sum to the GEMM epilogue (identical
// math). Softmax is recomputed per col-tile (4x redundant exp, negligible).
// ---------------------------------------------------------------------------
__global__ __launch_bounds__(256)
void smctx_kernel(const float* __restrict__ sc, const float* __restrict__ prev,
                  float* __restrict__ ctx)
{
    __shared__ float Ws[256][68];   // Ws[m][r] = exp'd scores, transposed (pad 68)
    __shared__ float Bs[16][64];
    __shared__ float redm[4][64];
    __shared__ float reds[4][64];
    __shared__ float rmax[64];
    __shared__ float rinv[64];

    const int b = blockIdx.y;
    const int tile = blockIdx.x;
    const int row0 = (tile >> 2) * 64;
    const int col0 = (tile & 3) * 64;
    const int tid = threadIdx.x;
    const int r = tid & 63;
    const int q = tid >> 6;

    // load: thread owns cols q*64..q*64+63 of row (row0+r); write transposed
    const float* srow = sc + ((size_t)b * N_ + row0 + r) * N_ + q * 64;
    float lmax = -3.4e38f;
#pragma unroll
    for (int i = 0; i < 16; ++i) {
        float4 v = *(const float4*)&srow[4 * i];
        Ws[q * 64 + 4 * i + 0][r] = v.x;
        Ws[q * 64 + 4 * i + 1][r] = v.y;
        Ws[q * 64 + 4 * i + 2][r] = v.z;
        Ws[q * 64 + 4 * i + 3][r] = v.w;
        lmax = fmaxf(lmax, fmaxf(fmaxf(v.x, v.y), fmaxf(v.z, v.w)));
    }
    redm[q][r] = lmax;
    __syncthreads();
    if (tid < 64)
        rmax[tid] = fmaxf(fmaxf(redm[0][tid], redm[1][tid]),
                          fmaxf(redm[2][tid], redm[3][tid]));
    __syncthreads();
    {
        float m = rmax[r];
        float lsum = 0.f;
#pragma unroll 4
        for (int i = 0; i < 64; ++i) {
            float e = expf(Ws[q * 64 + i][r] - m);
            Ws[q * 64 + i][r] = e;
            lsum += e;
        }
        reds[q][r] = lsum;
    }
    __syncthreads();
    if (tid < 64)
        rinv[tid] = 1.0f / (reds[0][tid] + reds[1][tid] + reds[2][tid] + reds[3][tid]);
    // visibility of rinv & Ws guaranteed by syncs inside the GEMM loop

    const int tx = tid & 15, ty = tid >> 4;
    const int br = tid >> 4, bc = (tid & 15) * 4;
    float acc[4][4] = {};
    for (int kt = 0; kt < N_; kt += 16) {
        float4 bv = *(const float4*)&prev[((size_t)b * N_ + kt + br) * S_ + col0 + bc];
        __syncthreads();
        *(float4*)&Bs[br][bc] = bv;
        __syncthreads();
#pragma unroll
        for (int k = 0; k < 16; ++k) {
            float4 a = *(const float4*)&Ws[kt + k][ty * 4];
            float4 c = *(const float4*)&Bs[k][tx * 4];
            acc[0][0] += a.x * c.x; acc[0][1] += a.x * c.y; acc[0][2] += a.x * c.z; acc[0][3] += a.x * c.w;
            acc[1][0] += a.y * c.x; acc[1][1] += a.y * c.y; acc[1][2] += a.y * c.z; acc[1][3] += a.y * c.w;
            acc[2][0] += a.z * c.x; acc[2][1] += a.z * c.y; acc[2][2] += a.z * c.z; acc[2][3] += a.z * c.w;
            acc[3][0] += a.w * c.x; acc[3][1] += a.w * c.y; acc[3][2] += a.w * c.z; acc[3][3] += a.w * c.w;
        }
    }
#pragma unroll
    for (int i = 0; i < 4; ++i) {
        float inv = rinv[ty * 4 + i];
        float4 rr = make_float4(acc[i][0] * inv, acc[i][1] * inv,
                                acc[i][2] * inv, acc[i][3] * inv);
        *(float4*)&ctx[((size_t)b * N_ + row0 + ty * 4 + i) * S_ + col0 + tx * 4] = rr;
    }
}

// ---------------------------------------------------------------------------
// proj64: out[b][t][o] = prev[b][224:,:].flat @ w_proj[o] + b_proj[o]
// One wave per output o; shuffle reduction (no LDS tree / syncthreads).
// ---------------------------------------------------------------------------
__global__ __launch_bounds__(64)
void proj64_kernel(const float* __restrict__ prev, const float* __restrict__ wp,
                   const float* __restrict__ bp, float* __restrict__ out, int t)
{
    const int o = blockIdx.x;
    const int lane = threadIdx.x;
    const float* wr = wp + (size_t)o * (NIN_ * S_);
    float acc[8] = {};
    for (int i = lane * 4; i < NIN_ * S_; i += 256) {
        float4 w = *(const float4*)&wr[i];
#pragma unroll
        for (int b = 0; b < 8; ++b) {
            float4 p = *(const float4*)&prev[((size_t)b * N_ + (N_ - NIN_)) * S_ + i];
            acc[b] += w.x * p.x + w.y * p.y + w.z * p.z + w.w * p.w;
        }
    }
#pragma unroll
    for (int b = 0; b < 8; ++b)
        for (int off = 32; off > 0; off >>= 1)
            acc[b] += __shfl_down(acc[b], off);
    if (lane == 0) {
        float bv = bp[o];
#pragma unroll
        for (int b = 0; b < 8; ++b)
            out[((size_t)b * T_ + t) * OUTPUT_ + o] = acc[b] + bv;
    }
}

// ---------------------------------------------------------------------------
extern "C" void kernel_launch(void* const* d_in, const int* in_sizes, int n_in,
                              void* d_out, int out_size, void* d_ws, size_t ws_size,
                              hipStream_t stream)
{
    (void)in_sizes; (void)n_in; (void)out_size; (void)ws_size;
    const float* x    = (const float*)d_in[0];
    const float* w_ri = (const float*)d_in[1];
    const float* b_ri = (const float*)d_in[2];
    const float* w_ro = (const float*)d_in[3];
    const float* b_ro = (const float*)d_in[4];
    const float* w_ih = (const float*)d_in[5];
    const float* b_ih = (const float*)d_in[6];
    const float* w_hh = (const float*)d_in[7];
    const float* b_hh = (const float*)d_in[8];
    const float* w_q  = (const float*)d_in[9];
    const float* b_q  = (const float*)d_in[10];
    const float* w_k  = (const float*)d_in[11];
    const float* b_k  = (const float*)d_in[12];
    const float* w_s  = (const float*)d_in[13];
    const float* b_s  = (const float*)d_in[14];
    const float* w_p  = (const float*)d_in[15];
    const float* b_p  = (const float*)d_in[16];
    float* out = (float*)d_out;

    float* ws = (float*)d_ws;
    const size_t SZ = (size_t)B_ * N_ * H_; // 524288 floats = 2 MB
    float* hbuf = ws;
    float* cbuf = hbuf + SZ;
    float* prev = cbuf + SZ;
    float* Q    = prev + SZ;
    float* Kb   = Q + SZ;
    float* sc   = Kb + SZ;
    float* ctxb = sc + SZ;
    float* lin  = ctxb + SZ;
    float* rec_all = lin + SZ;  // [T][B][32][H] = 2*SZ floats (4 MB)

    hipMemsetAsync(d_ws, 0, 3 * SZ * sizeof(float), stream); // h, c, prev = 0

    // rec_in for all timesteps (x-only dependency)
    rec_in_all_kernel<<<dim3(NIN_, T_), 256, 0, stream>>>(x, w_ri, b_ri, rec_all);
    // Q,K for t=0 from h=0 (-> biases)
    pnmm256_kernel<<<dim3(256, 2), 256, 0, stream>>>(hbuf,
        w_q, b_q, Q, w_k, b_k, Kb, w_k, b_k, Kb, 0, 0, 0);

    for (int t = 0; t < T_; ++t) {
        scores_kernel<<<dim3(16, B_), 256, 0, stream>>>(Q, Kb, sc);
        smctx_kernel<<<dim3(16, B_), 256, 0, stream>>>(sc, prev, ctxb);
        // rec_other: lin[n>=32] = relu(ctx @ w_ro + b_ro)
        pnmm256_kernel<<<dim3(224, 1), 256, 0, stream>>>(ctxb,
            w_ro, b_ro, lin, w_ro, b_ro, lin, w_ro, b_ro, lin, NIN_, NIN_, 1);
        // gates + cell fused (updates hbuf, cbuf in place)
        gatescell_kernel<<<dim3(256), 512, 0, stream>>>(lin, rec_all, t,
            w_ih, w_hh, b_ih, b_hh, cbuf, hbuf);
        // prev = h_new @ w_s + b_s ; Q,K for next step from h_new (fused z=3)
        pnmm256_kernel<<<dim3(256, 3), 256, 0, stream>>>(hbuf,
            w_s, b_s, prev, w_q, b_q, Q, w_k, b_k, Kb, 0, 0, 0);
        proj64_kernel<<<dim3(OUTPUT_), 64, 0, stream>>>(prev, w_p, b_p, out, t);
    }
}

// Round 3
// 3893.443 us; speedup vs baseline: 1.1515x; 1.0074x over previous
//
#include <hip/hip_runtime.h>
#include <cmath>

#define DEV_INLINE __device__ __forceinline__

constexpr int B_ = 8, T_ = 16, INPUT_ = 64, OUTPUT_ = 128;
constexpr int N_ = 256, H_ = 256, KQ_ = 256, S_ = 256, G_ = 1024; // G_ = 4*H
constexpr int NIN_ = 32;
constexpr float SCALE_ = 0.0625f; // 1/sqrt(256)

DEV_INLINE float sigmoid_(float x) { return 1.0f / (1.0f + expf(-x)); }
DEV_INLINE void fma4(float4& a, const float4& w, float s) {
    a.x += w.x * s; a.y += w.y * s; a.z += w.z * s; a.w += w.w * s;
}

// ---------------------------------------------------------------------------
// out_mm256: O[b][n][hh] = sum_h hnew[h][b] * W[n][h][hh] + bias[n][hh]
// 512 threads: 2 K-splits x 256 cols (scalar col per thread), LDS reduce.
// ---------------------------------------------------------------------------
DEV_INLINE void out_mm256(int n, int tid, const float* __restrict__ W,
                          const float* __restrict__ bias, float* __restrict__ O,
                          const float* hnew, float* psum0, float* psum1)
{
    const int hcol = tid & 255;
    const int sp = tid >> 8;
    const float* wp = W + ((size_t)n * H_ + sp * 128) * 256 + hcol;
    float acc[8] = {};
    float wA[8], wB[8];
#pragma unroll
    for (int u = 0; u < 8; ++u) wA[u] = wp[(size_t)u * 256];
#pragma unroll 1
    for (int s0 = 0; s0 < 128; s0 += 8) {
        if (s0 + 8 < 128) {
#pragma unroll
            for (int u = 0; u < 8; ++u) wB[u] = wp[(size_t)(s0 + 8 + u) * 256];
        }
#pragma unroll
        for (int u = 0; u < 8; ++u) {
            float w = wA[u];
            const float* ip = &hnew[(sp * 128 + s0 + u) * 8];
            float4 i0 = *(const float4*)ip;
            float4 i1 = *(const float4*)(ip + 4);
            acc[0] += w * i0.x; acc[1] += w * i0.y; acc[2] += w * i0.z; acc[3] += w * i0.w;
            acc[4] += w * i1.x; acc[5] += w * i1.y; acc[6] += w * i1.z; acc[7] += w * i1.w;
        }
#pragma unroll
        for (int u = 0; u < 8; ++u) wA[u] = wB[u];
    }
    float* dst = sp ? psum1 : psum0;
    *(float4*)&dst[hcol * 8] = make_float4(acc[0], acc[1], acc[2], acc[3]);
    *(float4*)&dst[hcol * 8 + 4] = make_float4(acc[4], acc[5], acc[6], acc[7]);
    __syncthreads();
    for (int i = tid; i < 2048; i += 512) {
        int hh = i & 255, b = i >> 8;
        float v = psum0[hh * 8 + b] + psum1[hh * 8 + b] + bias[(size_t)n * H_ + hh];
        O[(size_t)(b * N_ + n) * H_ + hh] = v;
    }
    __syncthreads();
}

// ---------------------------------------------------------------------------
// neuron_step: per-neuron fused chain (one 512-thread block per n):
//   phase1: lin = relu(ctx @ w_ro + b_ro)   (n>=32; n<32 reads rec_all)
//   phase2: gates = lin @ w_ih + h @ w_hh   (2 K-splits x 4-col threads)
//   phase3: LDS reduce + biases + LSTM cell -> c, h (global + LDS)
//   phase4: prev/Q/K = h_new @ w_s/w_q/w_k + bias
// All per-n state (ctx row, h row, weights[n]) is block-local -> no global
// round-trips between phases; one kernel streams all 790 MB/step of weights.
// ---------------------------------------------------------------------------
__global__ __launch_bounds__(512)
void neuron_step_kernel(const float* __restrict__ ctx,
                        const float* __restrict__ rec_all, int t,
                        const float* __restrict__ w_ro, const float* __restrict__ b_ro,
                        const float* __restrict__ wih, const float* __restrict__ whh,
                        const float* __restrict__ bih, const float* __restrict__ bhh,
                        const float* __restrict__ w_s, const float* __restrict__ b_s,
                        const float* __restrict__ w_q, const float* __restrict__ b_q,
                        const float* __restrict__ w_k, const float* __restrict__ b_k,
                        float* __restrict__ c, float* __restrict__ h,
                        float* __restrict__ prev, float* __restrict__ Q,
                        float* __restrict__ K)
{
    const int n = blockIdx.x;
    const int tid = threadIdx.x;      // 0..511

    __shared__ float A[8192];         // 32 KB, phase-aliased
    __shared__ float Bh[2048];        // h_new [hh][b] (8 KB)
    float* sctx  = A;                 // [256][8] phase1 input
    float* shi   = A + 2048;          // [256][8] lstm_in
    float* shh   = A + 4096;          // [256][8] h_old
    float* spare = A + 6144;          // [256][8] phase1/4 partial
    float* glds  = A;                 // [8][1024] gates (phase3)

    // ---- phase 0: stage h (+ ctx or rec_all) ----
    for (int i = tid; i < 2048; i += 512) {
        int hh = i & 255, b = i >> 8;
        size_t off = (size_t)(b * N_ + n) * H_ + hh;
        shh[hh * 8 + b] = h[off];
        if (n < NIN_)
            shi[hh * 8 + b] = rec_all[(((size_t)t * 8 + b) * NIN_ + n) * H_ + hh];
        else
            sctx[hh * 8 + b] = ctx[off];
    }
    __syncthreads();

    // ---- phase 1: rec_other matmul (n>=32) ----
    if (n >= NIN_) {
        const int hcol = tid & 255;
        const int sp = tid >> 8;
        const float* wp = w_ro + ((size_t)(n - NIN_) * H_ + sp * 128) * 256 + hcol;
        float acc[8] = {};
        float wA[8], wB[8];
#pragma unroll
        for (int u = 0; u < 8; ++u) wA[u] = wp[(size_t)u * 256];
#pragma unroll 1
        for (int s0 = 0; s0 < 128; s0 += 8) {
            if (s0 + 8 < 128) {
#pragma unroll
                for (int u = 0; u < 8; ++u) wB[u] = wp[(size_t)(s0 + 8 + u) * 256];
            }
#pragma unroll
            for (int u = 0; u < 8; ++u) {
                float w = wA[u];
                const float* ip = &sctx[(sp * 128 + s0 + u) * 8];
                float4 i0 = *(const float4*)ip;
                float4 i1 = *(const float4*)(ip + 4);
                acc[0] += w * i0.x; acc[1] += w * i0.y; acc[2] += w * i0.z; acc[3] += w * i0.w;
                acc[4] += w * i1.x; acc[5] += w * i1.y; acc[6] += w * i1.z; acc[7] += w * i1.w;
            }
#pragma unroll
            for (int u = 0; u < 8; ++u) wA[u] = wB[u];
        }
        float* dst = sp ? spare : shi;
        *(float4*)&dst[hcol * 8] = make_float4(acc[0], acc[1], acc[2], acc[3]);
        *(float4*)&dst[hcol * 8 + 4] = make_float4(acc[4], acc[5], acc[6], acc[7]);
        __syncthreads();
        for (int i = tid; i < 2048; i += 512) {
            int hh = i & 255, b = i >> 8;
            float v = shi[hh * 8 + b] + spare[hh * 8 + b]
                    + b_ro[(size_t)(n - NIN_) * H_ + hh];
            shi[hh * 8 + b] = fmaxf(v, 0.f);
        }
    }
    __syncthreads();

    // ---- phase 2: gates matmul ----
    const int sp = tid >> 8;          // K split 0/1
    const int c0 = (tid & 255) * 4;   // gate col
    const int h0 = sp * 128;
    const float* wi = wih + ((size_t)n * H_ + h0) * G_ + c0;
    const float* wh = whh + ((size_t)n * H_ + h0) * G_ + c0;
    float4 acc[8] = {};
    {
        float4 biA[4], bhA[4], biB[4], bhB[4];
#pragma unroll
        for (int u = 0; u < 4; ++u) {
            biA[u] = *(const float4*)(wi + (size_t)u * G_);
            bhA[u] = *(const float4*)(wh + (size_t)u * G_);
        }
#pragma unroll 1
        for (int hb = 0; hb < 128; hb += 4) {
            if (hb + 4 < 128) {
#pragma unroll
                for (int u = 0; u < 4; ++u) {
                    biB[u] = *(const float4*)(wi + (size_t)(hb + 4 + u) * G_);
                    bhB[u] = *(const float4*)(wh + (size_t)(hb + 4 + u) * G_);
                }
            }
#pragma unroll
            for (int u = 0; u < 4; ++u) {
                float4 a = biA[u];
                float4 hv = bhA[u];
                const float* ip = &shi[(h0 + hb + u) * 8];
                const float* hp = &shh[(h0 + hb + u) * 8];
                float4 i0 = *(const float4*)ip;
                float4 i1 = *(const float4*)(ip + 4);
                float4 h0v = *(const float4*)hp;
                float4 h1v = *(const float4*)(hp + 4);
                fma4(acc[0], a, i0.x); fma4(acc[0], hv, h0v.x);
                fma4(acc[1], a, i0.y); fma4(acc[1], hv, h0v.y);
                fma4(acc[2], a, i0.z); fma4(acc[2], hv, h0v.z);
                fma4(acc[3], a, i0.w); fma4(acc[3], hv, h0v.w);
                fma4(acc[4], a, i1.x); fma4(acc[4], hv, h1v.x);
                fma4(acc[5], a, i1.y); fma4(acc[5], hv, h1v.y);
                fma4(acc[6], a, i1.z); fma4(acc[6], hv, h1v.z);
                fma4(acc[7], a, i1.w); fma4(acc[7], hv, h1v.w);
            }
#pragma unroll
            for (int u = 0; u < 4; ++u) { biA[u] = biB[u]; bhA[u] = bhB[u]; }
        }
    }
    __syncthreads();                  // staging dead; alias A into glds

    // ---- phase 3: reduce + biases + cell ----
    if (sp == 1) {
#pragma unroll
        for (int b = 0; b < 8; ++b)
            *(float4*)&glds[b * 1024 + c0] = acc[b];
    }
    __syncthreads();
    if (sp == 0) {
        float4 bi = *(const float4*)&bih[(size_t)n * G_ + c0];
        float4 bh = *(const float4*)&bhh[(size_t)n * G_ + c0];
#pragma unroll
        for (int b = 0; b < 8; ++b) {
            float4 g = *(const float4*)&glds[b * 1024 + c0];
            g.x += acc[b].x + bi.x + bh.x;
            g.y += acc[b].y + bi.y + bh.y;
            g.z += acc[b].z + bi.z + bh.z;
            g.w += acc[b].w + bi.w + bh.w;
            *(float4*)&glds[b * 1024 + c0] = g;
        }
    }
    __syncthreads();
    // gates layout [i(0:256) f(256:512) g(512:768) o(768:1024)]
#pragma unroll
    for (int e = 0; e < 4; ++e) {
        int idx = tid + 512 * e;      // 0..2047
        int b = idx >> 8, hx = idx & 255;
        float ig = glds[b * 1024 + 0   + hx];
        float fg = glds[b * 1024 + 256 + hx];
        float gg = glds[b * 1024 + 512 + hx];
        float og = glds[b * 1024 + 768 + hx];
        size_t off = (size_t)(b * N_ + n) * H_ + hx;
        float cv = c[off];
        float cn = sigmoid_(fg) * cv + sigmoid_(ig) * tanhf(gg);
        float hn = sigmoid_(og) * tanhf(cn);
        c[off] = cn;
        h[off] = hn;
        Bh[hx * 8 + b] = hn;
    }
    __syncthreads();                  // Bh ready; glds dead -> A reusable

    // ---- phase 4: prev / Q / K from h_new ----
    out_mm256(n, tid, w_s, b_s, prev, Bh, shi, spare);
    out_mm256(n, tid, w_q, b_q, Q,    Bh, shi, spare);
    out_mm256(n, tid, w_k, b_k, K,    Bh, shi, spare);
}

// ---------------------------------------------------------------------------
// rec_in_all: rec_all[t][b][n][h] = relu(x_t @ w_rec_input + b), all T upfront
// ---------------------------------------------------------------------------
__global__ __launch_bounds__(256)
void rec_in_all_kernel(const float* __restrict__ x,
                       const float* __restrict__ w_ri, const float* __restrict__ b_ri,
                       float* __restrict__ rec_all)
{
    __shared__ float sh[INPUT_ * 8];
    const int n = blockIdx.x;
    const int t = blockIdx.y;
    const int tid = threadIdx.x;
    for (int i = tid; i < INPUT_ * 8; i += 256) {
        int hh = i & 63, b = i >> 6;
        sh[hh * 8 + b] = x[((size_t)b * T_ + t) * INPUT_ + hh];
    }
    __syncthreads();
    const float* wp = w_ri + (size_t)n * INPUT_ * H_ + tid;
    float acc[8] = {};
#pragma unroll 8
    for (int hh = 0; hh < INPUT_; ++hh) {
        float w = wp[(size_t)hh * H_];
        float4 i0 = *(const float4*)&sh[hh * 8];
        float4 i1 = *(const float4*)&sh[hh * 8 + 4];
        acc[0] += w * i0.x; acc[1] += w * i0.y; acc[2] += w * i0.z; acc[3] += w * i0.w;
        acc[4] += w * i1.x; acc[5] += w * i1.y; acc[6] += w * i1.z; acc[7] += w * i1.w;
    }
    float bv = b_ri[n * H_ + tid];
#pragma unroll
    for (int b = 0; b < 8; ++b)
        rec_all[(((size_t)t * 8 + b) * NIN_ + n) * H_ + tid] = fmaxf(acc[b] + bv, 0.f);
}

// qkinit: h=0 -> Q/K are just broadcast biases
__global__ __launch_bounds__(256)
void qkinit_kernel(const float* __restrict__ b_q, const float* __restrict__ b_k,
                   float* __restrict__ Q, float* __restrict__ K)
{
    const int idx = (blockIdx.x * 256 + threadIdx.x) * 4; // over N_*KQ_ = 65536
    float4 qv = *(const float4*)&b_q[idx];
    float4 kv = *(const float4*)&b_k[idx];
#pragma unroll
    for (int b = 0; b < 8; ++b) {
        *(float4*)&Q[(size_t)b * N_ * KQ_ + idx] = qv;
        *(float4*)&K[(size_t)b * N_ * KQ_ + idx] = kv;
    }
}

// ---------------------------------------------------------------------------
// scores[b][n][m] = SCALE * sum_h Q[b][n][h] * K[b][m][h]   (A @ B^T, 64x64)
// ---------------------------------------------------------------------------
__global__ void scores_kernel(const float* __restrict__ Q, const float* __restrict__ Kb,
                              float* __restrict__ sc)
{
    __shared__ float As[16][64];
    __shared__ float Bs[16][64];
    const int b = blockIdx.y;
    const int tile = blockIdx.x;
    const int row0 = (tile >> 2) * 64;
    const int col0 = (tile & 3) * 64;
    const int tid = threadIdx.x;
    const int tx = tid & 15, ty = tid >> 4;
    const int lr = tid >> 2;
    const int kq = (tid & 3) * 4;
    const float* Qb = Q + (size_t)b * N_ * KQ_;
    const float* Kbb = Kb + (size_t)b * N_ * KQ_;
    float acc[4][4] = {};
    for (int kt = 0; kt < KQ_; kt += 16) {
        float4 av = *(const float4*)&Qb[(size_t)(row0 + lr) * KQ_ + kt + kq];
        float4 bv = *(const float4*)&Kbb[(size_t)(col0 + lr) * KQ_ + kt + kq];
        __syncthreads();
        As[kq + 0][lr] = av.x; As[kq + 1][lr] = av.y; As[kq + 2][lr] = av.z; As[kq + 3][lr] = av.w;
        Bs[kq + 0][lr] = bv.x; Bs[kq + 1][lr] = bv.y; Bs[kq + 2][lr] = bv.z; Bs[kq + 3][lr] = bv.w;
        __syncthreads();
#pragma unroll
        for (int k = 0; k < 16; ++k) {
            float4 a = *(const float4*)&As[k][ty * 4];
            float4 c = *(const float4*)&Bs[k][tx * 4];
            acc[0][0] += a.x * c.x; acc[0][1] += a.x * c.y; acc[0][2] += a.x * c.z; acc[0][3] += a.x * c.w;
            acc[1][0] += a.y * c.x; acc[1][1] += a.y * c.y; acc[1][2] += a.y * c.z; acc[1][3] += a.y * c.w;
            acc[2][0] += a.z * c.x; acc[2][1] += a.z * c.y; acc[2][2] += a.z * c.z; acc[2][3] += a.z * c.w;
            acc[3][0] += a.w * c.x; acc[3][1] += a.w * c.y; acc[3][2] += a.w * c.z; acc[3][3] += a.w * c.w;
        }
    }
#pragma unroll
    for (int i = 0; i < 4; ++i) {
        float4 r = make_float4(acc[i][0] * SCALE_, acc[i][1] * SCALE_,
                               acc[i][2] * SCALE_, acc[i][3] * SCALE_);
        *(float4*)&sc[((size_t)b * N_ + row0 + ty * 4 + i) * N_ + col0 + tx * 4] = r;
    }
}

// ---------------------------------------------------------------------------
// smctx: ctx = softmax(sc, axis=m) @ prev, fused (1/sum deferred to epilogue)
// ---------------------------------------------------------------------------
__global__ __launch_bounds__(256)
void smctx_kernel(const float* __restrict__ sc, const float* __restrict__ prev,
                  float* __restrict__ ctx)
{
    __shared__ float Ws[256][68];
    __shared__ float Bs[16][64];
    __shared__ float redm[4][64];
    __shared__ float reds[4][64];
    __shared__ float rmax[64];
    __shared__ float rinv[64];

    const int b = blockIdx.y;
    const int tile = blockIdx.x;
    const int row0 = (tile >> 2) * 64;
    const int col0 = (tile & 3) * 64;
    const int tid = threadIdx.x;
    const int r = tid & 63;
    const int q = tid >> 6;

    const float* srow = sc + ((size_t)b * N_ + row0 + r) * N_ + q * 64;
    float lmax = -3.4e38f;
#pragma unroll
    for (int i = 0; i < 16; ++i) {
        float4 v = *(const float4*)&srow[4 * i];
        Ws[q * 64 + 4 * i + 0][r] = v.x;
        Ws[q * 64 + 4 * i + 1][r] = v.y;
        Ws[q * 64 + 4 * i + 2][r] = v.z;
        Ws[q * 64 + 4 * i + 3][r] = v.w;
        lmax = fmaxf(lmax, fmaxf(fmaxf(v.x, v.y), fmaxf(v.z, v.w)));
    }
    redm[q][r] = lmax;
    __syncthreads();
    if (tid < 64)
        rmax[tid] = fmaxf(fmaxf(redm[0][tid], redm[1][tid]),
                          fmaxf(redm[2][tid], redm[3][tid]));
    __syncthreads();
    {
        float m = rmax[r];
        float lsum = 0.f;
#pragma unroll 4
        for (int i = 0; i < 64; ++i) {
            float e = expf(Ws[q * 64 + i][r] - m);
            Ws[q * 64 + i][r] = e;
            lsum += e;
        }
        reds[q][r] = lsum;
    }
    __syncthreads();
    if (tid < 64)
        rinv[tid] = 1.0f / (reds[0][tid] + reds[1][tid] + reds[2][tid] + reds[3][tid]);

    const int tx = tid & 15, ty = tid >> 4;
    const int br = tid >> 4, bc = (tid & 15) * 4;
    float acc[4][4] = {};
    for (int kt = 0; kt < N_; kt += 16) {
        float4 bv = *(const float4*)&prev[((size_t)b * N_ + kt + br) * S_ + col0 + bc];
        __syncthreads();
        *(float4*)&Bs[br][bc] = bv;
        __syncthreads();
#pragma unroll
        for (int k = 0; k < 16; ++k) {
            float4 a = *(const float4*)&Ws[kt + k][ty * 4];
            float4 c = *(const float4*)&Bs[k][tx * 4];
            acc[0][0] += a.x * c.x; acc[0][1] += a.x * c.y; acc[0][2] += a.x * c.z; acc[0][3] += a.x * c.w;
            acc[1][0] += a.y * c.x; acc[1][1] += a.y * c.y; acc[1][2] += a.y * c.z; acc[1][3] += a.y * c.w;
            acc[2][0] += a.z * c.x; acc[2][1] += a.z * c.y; acc[2][2] += a.z * c.z; acc[2][3] += a.z * c.w;
            acc[3][0] += a.w * c.x; acc[3][1] += a.w * c.y; acc[3][2] += a.w * c.z; acc[3][3] += a.w * c.w;
        }
    }
#pragma unroll
    for (int i = 0; i < 4; ++i) {
        float inv = rinv[ty * 4 + i];
        float4 rr = make_float4(acc[i][0] * inv, acc[i][1] * inv,
                                acc[i][2] * inv, acc[i][3] * inv);
        *(float4*)&ctx[((size_t)b * N_ + row0 + ty * 4 + i) * S_ + col0 + tx * 4] = rr;
    }
}

// ---------------------------------------------------------------------------
// proj64: out[b][t][o] = prev[b][224:,:].flat @ w_proj[o] + b_proj[o]
// ---------------------------------------------------------------------------
__global__ __launch_bounds__(64)
void proj64_kernel(const float* __restrict__ prev, const float* __restrict__ wp,
                   const float* __restrict__ bp, float* __restrict__ out, int t)
{
    const int o = blockIdx.x;
    const int lane = threadIdx.x;
    const float* wr = wp + (size_t)o * (NIN_ * S_);
    float acc[8] = {};
    for (int i = lane * 4; i < NIN_ * S_; i += 256) {
        float4 w = *(const float4*)&wr[i];
#pragma unroll
        for (int b = 0; b < 8; ++b) {
            float4 p = *(const float4*)&prev[((size_t)b * N_ + (N_ - NIN_)) * S_ + i];
            acc[b] += w.x * p.x + w.y * p.y + w.z * p.z + w.w * p.w;
        }
    }
#pragma unroll
    for (int b = 0; b < 8; ++b)
        for (int off = 32; off > 0; off >>= 1)
            acc[b] += __shfl_down(acc[b], off);
    if (lane == 0) {
        float bv = bp[o];
#pragma unroll
        for (int b = 0; b < 8; ++b)
            out[((size_t)b * T_ + t) * OUTPUT_ + o] = acc[b] + bv;
    }
}

// ---------------------------------------------------------------------------
extern "C" void kernel_launch(void* const* d_in, const int* in_sizes, int n_in,
                              void* d_out, int out_size, void* d_ws, size_t ws_size,
                              hipStream_t stream)
{
    (void)in_sizes; (void)n_in; (void)out_size; (void)ws_size;
    const float* x    = (const float*)d_in[0];
    const float* w_ri = (const float*)d_in[1];
    const float* b_ri = (const float*)d_in[2];
    const float* w_ro = (const float*)d_in[3];
    const float* b_ro = (const float*)d_in[4];
    const float* w_ih = (const float*)d_in[5];
    const float* b_ih = (const float*)d_in[6];
    const float* w_hh = (const float*)d_in[7];
    const float* b_hh = (const float*)d_in[8];
    const float* w_q  = (const float*)d_in[9];
    const float* b_q  = (const float*)d_in[10];
    const float* w_k  = (const float*)d_in[11];
    const float* b_k  = (const float*)d_in[12];
    const float* w_s  = (const float*)d_in[13];
    const float* b_s  = (const float*)d_in[14];
    const float* w_p  = (const float*)d_in[15];
    const float* b_p  = (const float*)d_in[16];
    float* out = (float*)d_out;

    float* ws = (float*)d_ws;
    const size_t SZ = (size_t)B_ * N_ * H_; // 524288 floats = 2 MB
    float* hbuf = ws;
    float* cbuf = hbuf + SZ;
    float* prev = cbuf + SZ;
    float* Q    = prev + SZ;
    float* Kb   = Q + SZ;
    float* sc   = Kb + SZ;
    float* ctxb = sc + SZ;
    float* rec_all = ctxb + SZ;  // [T][B][32][H] = 2*SZ floats (4 MB)

    hipMemsetAsync(d_ws, 0, 3 * SZ * sizeof(float), stream); // h, c, prev = 0

    rec_in_all_kernel<<<dim3(NIN_, T_), 256, 0, stream>>>(x, w_ri, b_ri, rec_all);
    qkinit_kernel<<<dim3(64), 256, 0, stream>>>(b_q, b_k, Q, Kb);

    for (int t = 0; t < T_; ++t) {
        scores_kernel<<<dim3(16, B_), 256, 0, stream>>>(Q, Kb, sc);
        smctx_kernel<<<dim3(16, B_), 256, 0, stream>>>(sc, prev, ctxb);
        neuron_step_kernel<<<dim3(N_), 512, 0, stream>>>(ctxb, rec_all, t,
            w_ro, b_ro, w_ih, w_hh, b_ih, b_hh,
            w_s, b_s, w_q, b_q, w_k, b_k,
            cbuf, hbuf, prev, Q, Kb);
        proj64_kernel<<<dim3(OUTPUT_), 64, 0, stream>>>(prev, w_p, b_p, out, t);
    }
}